// Round 2
// baseline (241.584 us; speedup 1.0000x reference)
//
#include <hip/hip_runtime.h>

// FourierFFTLayer: ifft(fft(x, axis=-1)).real on real float32 input ==
// identity (FFT round-trip error ~1e-2 absmax vs 1.08e-1 threshold).
//
// History / evidence:
//  R0: 1-float4/thread plain copy            -> 219.0 us headline
//  R1: 8-float4/thread + NONTEMPORAL         -> 230.7 us (REGRESSION)
//      Fills unchanged (79-80us both rounds) => our copy slowed ~12us.
//      Diagnosis: nt flag bypasses L2/LLC. Input (134MB) is static and
//      fits the 256MB Infinity Cache -> nt loads forfeit LLC hits; nt
//      stores forfeit L2 absorption of the just-poisoned output lines.
//  R2 (this): keep batch-of-8 + exact-fit grid, DROP nt. Clean A/B:
//      R0 vs R2 isolates batching, R1 vs R2 isolates nt.
//
// Timed-region structure (rocprof): ~2x 80us harness poison fills
// (fillBufferAligned, 512MB each, 84% HBM peak) are the floor we cannot
// touch; our copy (268MB ideal -> ~40-43us at copy ceiling) is the rest.

typedef float f32x4 __attribute__((ext_vector_type(4)));

__global__ __launch_bounds__(256) void identity_copy_b8(
        const f32x4* __restrict__ in, f32x4* __restrict__ out, int n4) {
    const int nth = gridDim.x * blockDim.x;
    int i = blockIdx.x * blockDim.x + threadIdx.x;

    // 8 float4s per thread; all 8 loads issued before the stores so 8
    // global_load_dwordx4 are in flight per thread (memory-level parallelism).
    // Each instruction is perfectly coalesced: lane l reads base + l.
    for (; i + 7 * nth < n4; i += 8 * nth) {
        f32x4 v0 = in[i + 0 * nth];
        f32x4 v1 = in[i + 1 * nth];
        f32x4 v2 = in[i + 2 * nth];
        f32x4 v3 = in[i + 3 * nth];
        f32x4 v4 = in[i + 4 * nth];
        f32x4 v5 = in[i + 5 * nth];
        f32x4 v6 = in[i + 6 * nth];
        f32x4 v7 = in[i + 7 * nth];
        out[i + 0 * nth] = v0;
        out[i + 1 * nth] = v1;
        out[i + 2 * nth] = v2;
        out[i + 3 * nth] = v3;
        out[i + 4 * nth] = v4;
        out[i + 5 * nth] = v5;
        out[i + 6 * nth] = v6;
        out[i + 7 * nth] = v7;
    }
    // Tail (empty for the exact-fit launch below, kept for safety).
    for (; i < n4; i += nth) {
        out[i] = in[i];
    }
}

extern "C" void kernel_launch(void* const* d_in, const int* in_sizes, int n_in,
                              void* d_out, int out_size, void* d_ws, size_t ws_size,
                              hipStream_t stream) {
    (void)in_sizes; (void)n_in; (void)d_ws; (void)ws_size;
    const f32x4* x = (const f32x4*)d_in[0];
    f32x4* out = (f32x4*)d_out;
    int n4 = out_size / 4;  // 33554432 floats / 4 = 8388608 float4s

    const int block = 256;
    const int per_thread = 8;
    // Exact fit for n4 = 8388608: 8388608 / (256*8) = 4096 blocks
    // (16 blocks/CU; plenty of waves to saturate HBM).
    int grid = (n4 + block * per_thread - 1) / (block * per_thread);
    identity_copy_b8<<<grid, block, 0, stream>>>(x, out, n4);
}

// Round 3
// 227.457 us; speedup vs baseline: 1.0621x; 1.0621x over previous
//
#include <hip/hip_runtime.h>

// FourierFFTLayer: ifft(fft(x, axis=-1)).real on real float32 == identity
// (FFT round-trip error absmax ~1.6e-2 vs 1.08e-1 threshold).
//
// Evidence ledger (headline = 2 harness poison fills @80us + our copy):
//  R0: simple 1-f4/thread, 32768 blk      copy ~59us  (219.0 headline)
//  R1: batch-8, stride=16MB, NT           copy ~70us  (230.7)
//  R2: batch-8, stride=16MB, plain        copy  92us  (241.6)
//      rocprof R2: FETCH=64MB (half input LLC-resident!), WRITE=128MB,
//      HBM 2.17 TB/s, VALUBusy 1.2%, no bank conflicts.
//  Diagnosis: 16MB-strided batch scatters every wave's 8 accesses across
//  the whole 128MB buffer -> DRAM row-buffer + LLC locality destroyed.
//  R0's win came from a compact sweeping access window, not from lack of
//  batching. NT helped R1 only by masking L2 thrash of the scatter.
//
// R3: batch-8 with BLOCK-CONTIGUOUS chunks. Block b owns a contiguous
// 32KB chunk (2048 float4s); thread t does chunk + t + k*256, k=0..7.
// Per-instruction: lanes contiguous (1KB segments). Per-wave: 8 in-flight
// accesses 4KB apart WITHIN the chunk. Keeps MLP=8 + compact footprint.

typedef float f32x4 __attribute__((ext_vector_type(4)));

#ifndef PER_THREAD
#define PER_THREAD 8
#endif

__global__ __launch_bounds__(256) void identity_copy_chunk8(
        const f32x4* __restrict__ in, f32x4* __restrict__ out, int n4) {
    const int chunk = blockDim.x * PER_THREAD;          // 2048 float4s = 32KB
    int base = blockIdx.x * chunk + threadIdx.x;

    if (base + (PER_THREAD - 1) * blockDim.x < n4) {
        f32x4 v[PER_THREAD];
#pragma unroll
        for (int k = 0; k < PER_THREAD; ++k)
            v[k] = in[base + k * blockDim.x];           // 8 loads in flight
#pragma unroll
        for (int k = 0; k < PER_THREAD; ++k)
            out[base + k * blockDim.x] = v[k];
    } else {
        // Tail (unused for exact-fit launch; kept for safety).
        for (int i = base; i < n4; i += blockDim.x)
            out[i] = in[i];
    }
}

extern "C" void kernel_launch(void* const* d_in, const int* in_sizes, int n_in,
                              void* d_out, int out_size, void* d_ws, size_t ws_size,
                              hipStream_t stream) {
    (void)in_sizes; (void)n_in; (void)d_ws; (void)ws_size;
    const f32x4* x = (const f32x4*)d_in[0];
    f32x4* out = (f32x4*)d_out;
    int n4 = out_size / 4;  // 33554432 floats / 4 = 8388608 float4s

    const int block = 256;
    const int chunk = block * PER_THREAD;   // 2048 float4s per block
    // Exact fit: 8388608 / 2048 = 4096 blocks (16/CU, two resident rounds
    // sweeping the buffer front-to-back).
    int grid = (n4 + chunk - 1) / chunk;
    identity_copy_chunk8<<<grid, block, 0, stream>>>(x, out, n4);
}

// Round 4
// 220.925 us; speedup vs baseline: 1.0935x; 1.0296x over previous
//
#include <hip/hip_runtime.h>

// FourierFFTLayer: ifft(fft(x, axis=-1)).real on real float32 == identity
// (FFT round-trip absmax ~1.6e-2 vs 1.08e-1 threshold).
//
// Evidence ledger (headline = ~160us harness poison fills + our copy):
//  R0: 1-f4/thread, 32768 blk, plain       copy ~59us  (219.0)  << best
//  R1: batch-8 stride-16MB, NT both        copy ~70us  (230.7)
//  R2: batch-8 stride-16MB, plain          copy ~82us  (241.6)  FETCH=64MB
//  R3: batch-8 chunked-32KB, plain         copy ~67us  (227.5)
//  Conclusions: (a) per-thread batching hurts in every arrangement; the
//  R0 one-shot sweep (block dispatcher = sequential address stream) wins.
//  (b) NT vs plain on the same pattern (R1 vs R2): NT was 22us FASTER ->
//  NT path is fine; cache churn is real. (c) half the input is
//  LLC-resident (FETCH 64MB vs 134MB input).
//
// R4: R0's exact structure + NONTEMPORAL STORES ONLY. Plain loads keep the
// LLC input hits; NT stores skip write-allocate so 134MB of output lines
// stop evicting the input from L2/LLC. Output is re-poisoned by the
// harness every iteration -- caching it has zero value.

typedef float f32x4 __attribute__((ext_vector_type(4)));

__global__ __launch_bounds__(256) void identity_copy_ntst(
        const f32x4* __restrict__ in, f32x4* __restrict__ out, int n4) {
    int i = blockIdx.x * blockDim.x + threadIdx.x;
    int stride = gridDim.x * blockDim.x;
    for (; i < n4; i += stride) {
        f32x4 v = in[i];                          // plain load: use LLC hits
        __builtin_nontemporal_store(v, out + i);  // NT store: no write-allocate
    }
}

extern "C" void kernel_launch(void* const* d_in, const int* in_sizes, int n_in,
                              void* d_out, int out_size, void* d_ws, size_t ws_size,
                              hipStream_t stream) {
    (void)in_sizes; (void)n_in; (void)d_ws; (void)ws_size;
    const f32x4* x = (const f32x4*)d_in[0];
    f32x4* out = (f32x4*)d_out;
    int n4 = out_size / 4;  // 8388608 float4s

    const int block = 256;
    int grid = (n4 + block - 1) / block;  // 32768 blocks, one float4/thread
    identity_copy_ntst<<<grid, block, 0, stream>>>(x, out, n4);
}